// Round 4
// baseline (213.903 us; speedup 1.0000x reference)
//
#include <hip/hip_runtime.h>
#include <hip/hip_bf16.h>

// Problem: out = x @ W_eff^T + bias   (TOKENS=2048, N=4096, M=K=4096)
// W_eff = rownorm-rescaled Givens-rotated W; pairs are (2s,2s+1) adjacent,
// so row pair (2s,2s+1) and col pair (2t,2t+1) are closed 2x2 blocks.
//
// Norm identity: right rotations are orthogonal on the column space ->
// preserve each row's norm. So ||Wp row|| needs only ||w0||^2, ||w1||^2,
// <w0,w1> (3 reduced scalars), not the rotated data.
//
// Journal:
//  R1 (good): 128x128 BK=64 dbuf + counted vmcnt(8) + T2 both-sides swizzle:
//     gemm 95.3 -> 71.4 us (962 TF, MfmaUtil 40%, bank conflicts 0).
//  R2 (FAILED): 2-phase split with ds_reads issued AFTER the barrier and
//     drained immediately (zero DS-latency cover) + 3 barriers/tile:
//     71 -> 107 us. Lesson: phase reads must issue BEFORE the barrier.
//  R3: R1 gemm verbatim (75.4 us this run; 71-75 band) + sincos folded
//     into prelude. Total 208.7.
//  R4 (this): faithful 8-phase-template port at 128x256/8-wave:
//     tri-buffer LDS (144 KB), stage-2-ahead, vmcnt(6)/K-tile,
//     2 kk-phases x {8 ds_read -> 3 glds -> BAR -> lgkm(0) -> 16 MFMA}.

#define GK 4096      // inner dim (M in reference)
#define GN 4096      // output cols (N rows of W)
#define GT 2048      // tokens
#define NPAIR 2048   // S

typedef __bf16 bf16x8 __attribute__((ext_vector_type(8)));
typedef float  f32x4  __attribute__((ext_vector_type(4)));

static __device__ __forceinline__ unsigned short f2bf(float f) {
    union { float f; unsigned int u; } v; v.f = f;
    unsigned int r = v.u + 0x7fffu + ((v.u >> 16) & 1u);   // RNE
    return (unsigned short)(r >> 16);
}
static __device__ __forceinline__ unsigned int pack2bf(float a, float b) {
    return (unsigned int)f2bf(a) | ((unsigned int)f2bf(b) << 16);
}

// ---------------- Fused prelude ----------------
// blocks [0, 2048): build W_eff row pair s (bf16), single pass over W.
//   theta_R sincos computed inline (8 pairs/thread).
// blocks [2048, 4096): convert a 32 KB slice of x to bf16.
__global__ __launch_bounds__(256) void prelude(
    const float* __restrict__ W, const float* __restrict__ thL,
    const float* __restrict__ thR, const float* __restrict__ ecd,
    const float* __restrict__ x,
    unsigned short* __restrict__ Weff, unsigned short* __restrict__ Xbf)
{
    const int tid = threadIdx.x;

    if (blockIdx.x >= 2048) {
        // ---- x f32 -> bf16 ----
        const int cb = blockIdx.x - 2048;
        const size_t base = (size_t)cb * 512;             // 8-float chunk index
        const float4* X4 = (const float4*)x;
        uint4* O4 = (uint4*)Xbf;
#pragma unroll
        for (int k = 0; k < 2; k++) {
            const size_t m = base + tid + k * 256;
            const float4 a = X4[2 * m];
            const float4 b = X4[2 * m + 1];
            uint4 o;
            o.x = pack2bf(a.x, a.y);
            o.y = pack2bf(a.z, a.w);
            o.z = pack2bf(b.x, b.y);
            o.w = pack2bf(b.z, b.w);
            O4[m] = o;
        }
        return;
    }

    // ---- W_eff for row pair s ----
    const int s  = blockIdx.x;
    const int i0 = 2 * s, i1 = 2 * s + 1;

    const float tl = thL[s];
    const float cL = cosf(tl), sL = sinf(tl);

    float4 b0[4], b1[4];                        // rotated rows (held)
    float s00 = 0.f, s11 = 0.f, s01 = 0.f;      // ||w0||^2, ||w1||^2, <w0,w1>

    const float4* r0 = (const float4*)(W + (size_t)i0 * GK);
    const float4* r1 = (const float4*)(W + (size_t)i1 * GK);
    const float2* T2 = (const float2*)thR;      // (thR[2t], thR[2t+1]) per float4 of cols

#pragma unroll
    for (int k = 0; k < 4; k++) {
        const int c4 = tid + k * 256;           // float4 index: cols 4*c4 .. +3
        const float4 w0 = r0[c4];
        const float4 w1 = r1[c4];
        const float2 tt = T2[c4];               // thetas for col pairs 2*c4, 2*c4+1
        float4 cs;                              // cR0,sR0,cR1,sR1
        sincosf(tt.x, &cs.y, &cs.x);
        sincosf(tt.y, &cs.w, &cs.z);
        s00 += w0.x * w0.x + w0.y * w0.y + w0.z * w0.z + w0.w * w0.w;
        s11 += w1.x * w1.x + w1.y * w1.y + w1.z * w1.z + w1.w * w1.w;
        s01 += w0.x * w1.x + w0.y * w1.y + w0.z * w1.z + w0.w * w1.w;
        // left rotation (row mix)
        const float a0x = cL * w0.x - sL * w1.x;
        const float a0y = cL * w0.y - sL * w1.y;
        const float a0z = cL * w0.z - sL * w1.z;
        const float a0w = cL * w0.w - sL * w1.w;
        const float a1x = sL * w0.x + cL * w1.x;
        const float a1y = sL * w0.y + cL * w1.y;
        const float a1z = sL * w0.z + cL * w1.z;
        const float a1w = sL * w0.w + cL * w1.w;
        // right rotation (col mix within (x,y) and (z,w))
        b0[k].x = cs.x * a0x - cs.y * a0y;
        b0[k].y = cs.y * a0x + cs.x * a0y;
        b0[k].z = cs.z * a0z - cs.w * a0w;
        b0[k].w = cs.w * a0z + cs.z * a0w;
        b1[k].x = cs.x * a1x - cs.y * a1y;
        b1[k].y = cs.y * a1x + cs.x * a1y;
        b1[k].z = cs.z * a1z - cs.w * a1w;
        b1[k].w = cs.w * a1z + cs.z * a1w;
    }

    // block reduction of 3 sums
#pragma unroll
    for (int off = 32; off; off >>= 1) {
        s00 += __shfl_down(s00, off);
        s11 += __shfl_down(s11, off);
        s01 += __shfl_down(s01, off);
    }
    __shared__ float red[3][4];
    __shared__ float scales[2];
    const int wave = tid >> 6, lane = tid & 63;
    if (lane == 0) { red[0][wave] = s00; red[1][wave] = s11; red[2][wave] = s01; }
    __syncthreads();
    if (tid == 0) {
        const float t0 = red[0][0] + red[0][1] + red[0][2] + red[0][3];
        const float t1 = red[1][0] + red[1][1] + red[1][2] + red[1][3];
        const float td = red[2][0] + red[2][1] + red[2][2] + red[2][3];
        // rotated row norms, analytic (right rotations preserve row norms)
        const float n0 = cL * cL * t0 + sL * sL * t1 - 2.f * cL * sL * td;
        const float n1 = sL * sL * t0 + cL * cL * t1 + 2.f * cL * sL * td;
        scales[0] = sqrtf(t0) * expf(ecd[i0]) / (sqrtf(n0) + 1e-8f);
        scales[1] = sqrtf(t1) * expf(ecd[i1]) / (sqrtf(n1) + 1e-8f);
    }
    __syncthreads();
    const float sc0 = scales[0], sc1 = scales[1];

    uint2* o0 = (uint2*)(Weff + (size_t)i0 * GK);   // 4 bf16 = 8B per float4
    uint2* o1 = (uint2*)(Weff + (size_t)i1 * GK);
#pragma unroll
    for (int k = 0; k < 4; k++) {
        const int c4 = tid + k * 256;
        uint2 p0, p1;
        p0.x = pack2bf(b0[k].x * sc0, b0[k].y * sc0);
        p0.y = pack2bf(b0[k].z * sc0, b0[k].w * sc0);
        p1.x = pack2bf(b1[k].x * sc1, b1[k].y * sc1);
        p1.y = pack2bf(b1[k].z * sc1, b1[k].w * sc1);
        o0[c4] = p0;
        o1[c4] = p1;
    }
}

// ---------------- GEMM  out = Xbf @ Weff^T + bias ----------------
// R4 structure (template-faithful phase schedule):
//   BM=128 x BN=256 x BK=64, 512 thr / 8 waves (2M x 4N), per-wave 64x64.
//   Grid 16x16 = 256 blocks = 1/CU.  Tri-buffered LDS (144 KB),
//   stage-2-tiles-ahead, one counted s_waitcnt vmcnt(6) per K-tile.
//   Per K-tile: 2 phases (kk=0/1); phase = {8 ds_read_b128 issue ->
//   3 glds16 issue -> s_barrier -> lgkmcnt(0) -> setprio(1) 16 MFMA
//   setprio(0) -> s_barrier}.  ds_reads issue BEFORE the barrier (R2 fix):
//   DS latency hides under barrier skew + previous phase's MFMA drain.
//   T2 16B-slot XOR swizzle (pre-swizzled global source, linear LDS dest,
//   XOR'd ds_read) carried from R1 (verified 0 bank conflicts).
// Hazards: RAW = per-wave vmcnt(6) THEN barrier (covers cross-wave glds);
//   WAR = buf c's reads drained by phase-1 lgkmcnt(0) before any wave
//   passes the next iter-top barrier, after which re-staging glds issue.
static __device__ __forceinline__ void glds16(const unsigned short* g, unsigned short* l) {
    __builtin_amdgcn_global_load_lds(
        (const __attribute__((address_space(1))) unsigned int*)g,
        (__attribute__((address_space(3))) unsigned int*)l, 16, 0, 0);
}

__global__ __launch_bounds__(512, 2) void gemm_bt(
    const unsigned short* __restrict__ A,   // (GT, GK) bf16
    const unsigned short* __restrict__ B,   // (GN, GK) bf16
    const float* __restrict__ bias,
    float* __restrict__ C)                  // (GT, GN) f32
{
    constexpr int BM = 128, BN = 256, BK = 64;
    constexpr int NT = GK / BK;                 // 64 K-tiles
    __shared__ unsigned short As[3][BM * BK];   // 3 x 16 KB
    __shared__ unsigned short Bs[3][BN * BK];   // 3 x 32 KB   (144 KB total)

    const int tid  = threadIdx.x;
    const int lane = tid & 63;
    const int wave = tid >> 6;      // 0..7
    const int quad = lane >> 4;
    const int l16  = lane & 15;
    const int wm   = wave >> 2;     // 0..1  (M)
    const int wn   = wave & 3;      // 0..3  (N)
    const int bm   = blockIdx.y * BM;
    const int bn   = blockIdx.x * BN;
    // Note: flat id = y*16+x -> XCD = x%8, so all 16 M-blocks of an N-panel
    // share an XCD: B panels are naturally L2-local. No extra swizzle.

    // ---- staging addressing ----
    // One glds16 per wave covers 64 lanes x 16B = 8 rows of 128B.
    // Swizzle: physical 16B slot p of row r holds logical slot p ^ (r&7)
    // => lane fetches global slot (l&7)^lrow; LDS dest stays linear.
    const int lrow = lane >> 3;
    const int jlog = (lane & 7) ^ lrow;
    const unsigned short* gA[2];
    const unsigned short* gB[4];
    int lA[2], lB[4];
#pragma unroll
    for (int j = 0; j < 2; j++) {               // A: 16 chunks of 8 rows
        const int c = wave + j * 8;
        gA[j] = A + (size_t)(bm + c * 8 + lrow) * GK + jlog * 8;
        lA[j] = c * 512 + lane * 8;
    }
#pragma unroll
    for (int j = 0; j < 4; j++) {               // B: 32 chunks of 8 rows
        const int c = wave + j * 8;
        gB[j] = B + (size_t)(bn + c * 8 + lrow) * GK + jlog * 8;
        lB[j] = c * 512 + lane * 8;
    }

    // ds_read fragment addressing: logical 16B slot = kk*4+quad,
    // physical = (kk*4+quad) ^ (r&7), r&7 == l16&7 (row bases are x16).
#define READ_FRAGS(buf, kk) do {                                              \
    const int ps = (((kk) * 4 + quad) ^ (l16 & 7)) * 8;                       \
    _Pragma("unroll")                                                         \
    for (int i = 0; i < 4; i++)                                               \
        aF[i] = *(const bf16x8*)&As[buf][(wm * 64 + i * 16 + l16) * BK + ps]; \
    _Pragma("unroll")                                                         \
    for (int j = 0; j < 4; j++)                                               \
        bF[j] = *(const bf16x8*)&Bs[buf][(wn * 64 + j * 16 + l16) * BK + ps]; \
} while (0)

#define MFMA16 do {                                                           \
    _Pragma("unroll")                                                         \
    for (int i = 0; i < 4; i++)                                               \
        _Pragma("unroll")                                                     \
        for (int j = 0; j < 4; j++)                                           \
            acc[i][j] = __builtin_amdgcn_mfma_f32_16x16x32_bf16(              \
                aF[i], bF[j], acc[i][j], 0, 0, 0);                            \
} while (0)

    f32x4 acc[4][4] = {};

    // prologue: stage tiles 0 and 1 into bufs 0 and 1 (12 loads in flight)
#pragma unroll
    for (int tt = 0; tt < 2; tt++) {
        const int k0 = tt * BK;
        glds16(gA[0] + k0, &As[tt][lA[0]]);
        glds16(gA[1] + k0, &As[tt][lA[1]]);
        glds16(gB[0] + k0, &Bs[tt][lB[0]]);
        glds16(gB[1] + k0, &Bs[tt][lB[1]]);
        glds16(gB[2] + k0, &Bs[tt][lB[2]]);
        glds16(gB[3] + k0, &Bs[tt][lB[3]]);
    }

    int cur = 0, stg = 2;                       // read buf, stage buf
    for (int t = 0; t < NT - 1; ++t) {
        const int k2 = (t + 2) * BK;
        const bool do_stage = (t < NT - 2);
        // ---- iter top: tile t resident (all waves) ----
        asm volatile("s_waitcnt vmcnt(6)" ::: "memory");
        __builtin_amdgcn_s_barrier();
        __builtin_amdgcn_sched_barrier(0);
        // ---- phase 0 (kk=0) ----
        {
            bf16x8 aF[4], bF[4];
            READ_FRAGS(cur, 0);
            __builtin_amdgcn_sched_barrier(0);
            if (do_stage) {
                glds16(gA[0] + k2, &As[stg][lA[0]]);
                glds16(gA[1] + k2, &As[stg][lA[1]]);
                glds16(gB[0] + k2, &Bs[stg][lB[0]]);
            }
            __builtin_amdgcn_sched_barrier(0);
            __builtin_amdgcn_s_barrier();
            asm volatile("s_waitcnt lgkmcnt(0)" ::: "memory");
            __builtin_amdgcn_sched_barrier(0);
            __builtin_amdgcn_s_setprio(1);
            MFMA16;
            __builtin_amdgcn_s_setprio(0);
            __builtin_amdgcn_sched_barrier(0);
            __builtin_amdgcn_s_barrier();
        }
        // ---- phase 1 (kk=1) ----
        {
            bf16x8 aF[4], bF[4];
            READ_FRAGS(cur, 1);
            __builtin_amdgcn_sched_barrier(0);
            if (do_stage) {
                glds16(gB[1] + k2, &Bs[stg][lB[1]]);
                glds16(gB[2] + k2, &Bs[stg][lB[2]]);
                glds16(gB[3] + k2, &Bs[stg][lB[3]]);
            }
            __builtin_amdgcn_sched_barrier(0);
            __builtin_amdgcn_s_barrier();
            asm volatile("s_waitcnt lgkmcnt(0)" ::: "memory");
            __builtin_amdgcn_sched_barrier(0);
            __builtin_amdgcn_s_setprio(1);
            MFMA16;
            __builtin_amdgcn_s_setprio(0);
        }
        cur = (cur == 2) ? 0 : cur + 1;
        stg = (stg == 2) ? 0 : stg + 1;
    }
    // ---- final tile (t = NT-1) ----
    asm volatile("s_waitcnt vmcnt(0)" ::: "memory");
    __builtin_amdgcn_s_barrier();
    __builtin_amdgcn_sched_barrier(0);
    {
        bf16x8 aF[4], bF[4];
        READ_FRAGS(cur, 0);
        MFMA16;
    }
    {
        bf16x8 aF[4], bF[4];
        READ_FRAGS(cur, 1);
        MFMA16;
    }

#undef READ_FRAGS
#undef MFMA16

    // epilogue: C/D layout col=lane&15, row=quad*4+reg   (m89/m91 verified)
#pragma unroll
    for (int i = 0; i < 4; i++) {
        const int m = bm + wm * 64 + i * 16 + quad * 4;
#pragma unroll
        for (int j = 0; j < 4; j++) {
            const int n = bn + wn * 64 + j * 16 + l16;
            const float bv = bias[n];
#pragma unroll
            for (int r = 0; r < 4; r++)
                C[(size_t)(m + r) * GN + n] = acc[i][j][r] + bv;
        }
    }
}

extern "C" void kernel_launch(void* const* d_in, const int* in_sizes, int n_in,
                              void* d_out, int out_size, void* d_ws, size_t ws_size,
                              hipStream_t stream) {
    const float* x    = (const float*)d_in[0];
    const float* W    = (const float*)d_in[1];
    const float* bias = (const float*)d_in[2];
    const float* thL  = (const float*)d_in[3];
    const float* thR  = (const float*)d_in[4];
    const float* ecd  = (const float*)d_in[5];
    // pairs_L / pairs_R (d_in[6], d_in[7]) are fixed arange reshapes:
    // pair s = (2s, 2s+1) — exploited structurally above.

    unsigned short* Weff = (unsigned short*)d_ws;                                // 32 MB
    unsigned short* Xbf  = (unsigned short*)((char*)d_ws + (size_t)GN * GK * 2); // 16 MB

    float* out = (float*)d_out;

    prelude<<<dim3(4096), dim3(256), 0, stream>>>(W, thL, thR, ecd, x, Weff, Xbf);
    gemm_bt<<<dim3(GN / 256, GT / 128), dim3(512), 0, stream>>>(Xbf, Weff, bias, out);
}